// Round 2
// baseline (210.146 us; speedup 1.0000x reference)
//
#include <hip/hip_runtime.h>
#include <hip/hip_bf16.h>

// A=8 agents, B=64 envs, S=1024 seq, H=128 hidden.
#define AN 8
#define BN 64
#define SN 1024
#define HN 128
#define NSTRIPS ((AN * BN * SN) / 16)   // 32768 strips of 16 rows
#define GRID 2048
#define SPW 4                            // strips per wave (32768 / (2048*4 waves))

typedef __attribute__((ext_vector_type(8))) short bf16x8;
typedef __attribute__((ext_vector_type(4))) float f32x4;

__device__ __forceinline__ short f2bf(float f) {
    unsigned u = __builtin_bit_cast(unsigned, f);
    return (short)((u + 0x7fffu + ((u >> 16) & 1u)) >> 16);  // RNE
}

// Load one strip's rnn rows into 8 float4 regs (per-lane row r, k-slice kg).
#define RNLOAD(I, RN) do {                                                   \
    const int sr_ = ((sblk0 + (I)) << 4) + r;                                \
    const float* arow_ = rnn + ((size_t)sr_ * BN + b) * (AN * HN)            \
                             + a * HN + 8 * kg;                              \
    _Pragma("unroll")                                                        \
    for (int ks_ = 0; ks_ < 4; ++ks_) {                                      \
        RN[2 * ks_]     = *(const float4*)(arow_ + 32 * ks_);                \
        RN[2 * ks_ + 1] = *(const float4*)(arow_ + 32 * ks_ + 4);            \
    }                                                                        \
} while (0)

#define PROCESS(I, RN, PF) do {                                              \
    const int s0_ = (sblk0 + (I)) << 4;                                      \
    const size_t obase_ = (size_t)ab * (SN * HN)                             \
                        + (size_t)(s0_ + r) * HN + 4 * kg;                   \
    /* issue obs loads early — hidden under convert+MFMA */                  \
    float4 ob_[8];                                                           \
    _Pragma("unroll")                                                        \
    for (int mt_ = 0; mt_ < 8; ++mt_)                                        \
        ob_[mt_] = *(const float4*)(obs + obase_ + 16 * mt_);                \
    const float sc_ = scales[I];                                             \
    bf16x8 mb_[4];                                                           \
    _Pragma("unroll")                                                        \
    for (int ks_ = 0; ks_ < 4; ++ks_) {                                      \
        float4 lo_ = RN[2 * ks_], hi_ = RN[2 * ks_ + 1];                     \
        mb_[ks_][0] = f2bf(lo_.x * sc_); mb_[ks_][1] = f2bf(lo_.y * sc_);    \
        mb_[ks_][2] = f2bf(lo_.z * sc_); mb_[ks_][3] = f2bf(lo_.w * sc_);    \
        mb_[ks_][4] = f2bf(hi_.x * sc_); mb_[ks_][5] = f2bf(hi_.y * sc_);    \
        mb_[ks_][6] = f2bf(hi_.z * sc_); mb_[ks_][7] = f2bf(hi_.w * sc_);    \
    }                                                                        \
    PF; /* prefetch next strip's rnn while MFMA runs */                      \
    f32x4 acc_[8];                                                           \
    _Pragma("unroll")                                                        \
    for (int mt_ = 0; mt_ < 8; ++mt_) acc_[mt_] = (f32x4){0.f,0.f,0.f,0.f};  \
    _Pragma("unroll")                                                        \
    for (int ks_ = 0; ks_ < 4; ++ks_) {                                      \
        _Pragma("unroll")                                                    \
        for (int mt_ = 0; mt_ < 8; ++mt_)                                    \
            acc_[mt_] = __builtin_amdgcn_mfma_f32_16x16x32_bf16(             \
                Wfrag[mt_][ks_][lane], mb_[ks_], acc_[mt_], 0, 0, 0);        \
    }                                                                        \
    _Pragma("unroll")                                                        \
    for (int mt_ = 0; mt_ < 8; ++mt_) {                                      \
        float4 bi_ = *(const float4*)&bias_lds[16 * mt_ + 4 * kg];           \
        float4 o_  = ob_[mt_];                                               \
        float4 res_;                                                         \
        res_.x = acc_[mt_][0] + bi_.x + o_.x;                                \
        res_.y = acc_[mt_][1] + bi_.y + o_.y;                                \
        res_.z = acc_[mt_][2] + bi_.z + o_.z;                                \
        res_.w = acc_[mt_][3] + bi_.w + o_.w;                                \
        *(float4*)(out + obase_ + 16 * mt_) = res_;                          \
    }                                                                        \
} while (0)

__global__ __launch_bounds__(256) void commnet_fused(
    const float* __restrict__ obs,   // (A*B, S, H)
    const float* __restrict__ rnn,   // (S, B, A, H)
    const int*   __restrict__ alive, // (A, B, S, 1)
    const float* __restrict__ W,     // (H, H) [out, in]
    const float* __restrict__ bias,  // (H,)
    float* __restrict__ out)         // (A*B, S, H)
{
    // W fragments (used as MFMA A-operand): lane l of tile (mt,ks) holds
    // W[16*mt + (l&15)][32*ks + 8*(l>>4) + j], j=0..7 — identical packing
    // to R0's B-fragments (verified passing).
    __shared__ bf16x8 Wfrag[8][4][64];   // 32 KiB
    __shared__ float  bias_lds[HN];

    const int tid  = threadIdx.x;
    const int lane = tid & 63;
    const int wv   = tid >> 6;

    for (int e = tid; e < 8 * 4 * 64; e += 256) {
        int l  = e & 63;
        int ks = (e >> 6) & 3;
        int nt = e >> 8;
        int col = 16 * nt + (l & 15);
        int k0  = 32 * ks + 8 * (l >> 4);
        const float* wp = W + col * HN + k0;
        float4 w0 = *(const float4*)(wp);
        float4 w1 = *(const float4*)(wp + 4);
        bf16x8 f;
        f[0] = f2bf(w0.x); f[1] = f2bf(w0.y); f[2] = f2bf(w0.z); f[3] = f2bf(w0.w);
        f[4] = f2bf(w1.x); f[5] = f2bf(w1.y); f[6] = f2bf(w1.z); f[7] = f2bf(w1.w);
        Wfrag[nt][ks][l] = f;
    }
    if (tid < HN) bias_lds[tid] = bias[tid];
    __syncthreads();

    const int r  = lane & 15;  // strip row (seq offset) / D "col"
    const int kg = lane >> 4;  // k-group for A/B frags; D col-group

    // Each wave owns SPW consecutive strips; all share one (a,b) pair since
    // strip0 % 4 == 0 and 64 strips per (a,b).
    const int wave_id = blockIdx.x * 4 + wv;
    const int strip0  = wave_id * SPW;
    const int ab    = strip0 >> 6;
    const int sblk0 = strip0 & 63;
    const int a = ab >> 6;
    const int b = ab & 63;

    // Prologue: alive scales for all SPW strips (one memory phase per wave).
    float scales[SPW];
#pragma unroll
    for (int i = 0; i < SPW; ++i) {
        const int sr = ((sblk0 + i) << 4) + r;
        int asum = 0, mya = 0;
#pragma unroll
        for (int a2 = 0; a2 < AN; ++a2) {
            int v = alive[(a2 * BN + b) * SN + sr];
            asum += v;
            if (a2 == a) mya = v;
        }
        scales[i] = mya ? 1.0f / (float)(asum < 1 ? 1 : asum) : 0.0f;
    }

    // Software-pipelined main loop (ping-pong rnn buffers, static indexing).
    float4 rnA[8], rnB[8];
    RNLOAD(0, rnA);
    PROCESS(0, rnA, RNLOAD(1, rnB));
    PROCESS(1, rnB, RNLOAD(2, rnA));
    PROCESS(2, rnA, RNLOAD(3, rnB));
    PROCESS(3, rnB, (void)0);
}

extern "C" void kernel_launch(void* const* d_in, const int* in_sizes, int n_in,
                              void* d_out, int out_size, void* d_ws, size_t ws_size,
                              hipStream_t stream) {
    const float* obs   = (const float*)d_in[0];
    const float* rnn   = (const float*)d_in[1];
    const int*   alive = (const int*)d_in[2];
    const float* W     = (const float*)d_in[3];
    const float* bias  = (const float*)d_in[4];
    float* out = (float*)d_out;
    (void)in_sizes; (void)n_in; (void)d_ws; (void)ws_size; (void)out_size;

    commnet_fused<<<GRID, 256, 0, stream>>>(obs, rnn, alive, W, bias, out);
}

// Round 3
// 199.191 us; speedup vs baseline: 1.0550x; 1.0550x over previous
//
#include <hip/hip_runtime.h>
#include <hip/hip_bf16.h>

// A=8 agents, B=64 envs, S=1024 seq, H=128 hidden.
#define AN 8
#define BN 64
#define SN 1024
#define HN 128
// 32768 strips of 16 rows; a "pair" (2 waves, H split) owns 4 strips, s-major.
#define NPAIR 8192

typedef __attribute__((ext_vector_type(8))) short bf16x8;
typedef __attribute__((ext_vector_type(4))) float f32x4;

__device__ __forceinline__ short f2bf(float f) {
    unsigned u = __builtin_bit_cast(unsigned, f);
    return (short)((u + 0x7fffu + ((u >> 16) & 1u)) >> 16);  // RNE
}

__global__ __launch_bounds__(512, 8) void commnet_fused(
    const float* __restrict__ obs,   // (A*B, S, H)
    const float* __restrict__ rnn,   // (S, B, A, H)
    const int*   __restrict__ alive, // (A, B, S, 1)
    const float* __restrict__ W,     // (H, H) [out, in]
    const float* __restrict__ bias,  // (H,)
    float* __restrict__ out)         // (A*B, S, H)
{
    // W as MFMA A-operand fragments: lane l of tile (mt,ks) holds
    // W[16*mt + (l&15)][32*ks + 8*(l>>4) + j], j=0..7. (verified R0/R1)
    __shared__ bf16x8 Wfrag[8][4][64];   // 32 KiB
    __shared__ float  bias_lds[HN];

    const int tid  = threadIdx.x;
    const int lane = tid & 63;
    const int wv   = tid >> 6;        // 0..7
    const int pair = wv >> 1;         // 0..3
    const int half = wv & 1;          // output-column half

    for (int e = tid; e < 8 * 4 * 64; e += 512) {
        int l  = e & 63;
        int ks = (e >> 6) & 3;
        int nt = e >> 8;
        int col = 16 * nt + (l & 15);
        int k0  = 32 * ks + 8 * (l >> 4);
        const float* wp = W + col * HN + k0;
        float4 w0 = *(const float4*)(wp);
        float4 w1 = *(const float4*)(wp + 4);
        bf16x8 f;
        f[0] = f2bf(w0.x); f[1] = f2bf(w0.y); f[2] = f2bf(w0.z); f[3] = f2bf(w0.w);
        f[4] = f2bf(w1.x); f[5] = f2bf(w1.y); f[6] = f2bf(w1.z); f[7] = f2bf(w1.w);
        Wfrag[nt][ks][l] = f;
    }
    if (tid < HN) bias_lds[tid] = bias[tid];
    __syncthreads();

    const int r  = lane & 15;  // strip row (seq offset); D col (msg row)
    const int kg = lane >> 4;  // k-group; D row-group (out-col group)

    // s-major pair mapping: concurrent waves cover ALL (a,b) for a narrow
    // s-window -> dense DRAM coverage of rnn.
    const int P   = blockIdx.x * 4 + pair;   // 0..8191
    const int ab  = P & 511;
    const int a   = ab >> 6;
    const int b   = ab & 63;
    const int sb0 = P >> 9;                  // 0..15

#pragma unroll
    for (int i = 0; i < 4; ++i) {
        const int sblk = sb0 + 16 * i;       // 0..63
        const int s0   = sblk << 4;
        const int s_r  = s0 + r;

        // alive scale for this lane's row
        int asum = 0, mya = 0;
#pragma unroll
        for (int a2 = 0; a2 < AN; ++a2) {
            int v = alive[(a2 * BN + b) * SN + s_r];
            asum += v;
            if (a2 == a) mya = v;
        }
        const float scale = mya ? 1.0f / (float)(asum < 1 ? 1 : asum) : 0.0f;

        // rnn row -> bf16 B-fragments (scaled)
        const float* arow = rnn + ((size_t)s_r * BN + b) * (AN * HN)
                                + a * HN + 8 * kg;
        bf16x8 mb[4];
#pragma unroll
        for (int ks = 0; ks < 4; ++ks) {
            float4 lo = *(const float4*)(arow + 32 * ks);
            float4 hi = *(const float4*)(arow + 32 * ks + 4);
            mb[ks][0] = f2bf(lo.x * scale); mb[ks][1] = f2bf(lo.y * scale);
            mb[ks][2] = f2bf(lo.z * scale); mb[ks][3] = f2bf(lo.w * scale);
            mb[ks][4] = f2bf(hi.x * scale); mb[ks][5] = f2bf(hi.y * scale);
            mb[ks][6] = f2bf(hi.z * scale); mb[ks][7] = f2bf(hi.w * scale);
        }

        // MFMA: this wave's 4 output-col tiles (16x64 half)
        f32x4 acc[4];
#pragma unroll
        for (int m = 0; m < 4; ++m) acc[m] = (f32x4){0.f, 0.f, 0.f, 0.f};
#pragma unroll
        for (int ks = 0; ks < 4; ++ks) {
#pragma unroll
            for (int m = 0; m < 4; ++m)
                acc[m] = __builtin_amdgcn_mfma_f32_16x16x32_bf16(
                    Wfrag[4 * half + m][ks][lane], mb[ks], acc[m], 0, 0, 0);
        }

        // Epilogue: row = s0+r, cols = 64*half + 16*m + 4*kg + {0..3}
        const size_t obase = (size_t)ab * (SN * HN) + (size_t)s_r * HN
                           + 64 * half + 4 * kg;
#pragma unroll
        for (int m = 0; m < 4; ++m) {
            float4 o  = *(const float4*)(obs + obase + 16 * m);
            float4 bi = *(const float4*)&bias_lds[64 * half + 16 * m + 4 * kg];
            float4 res;
            res.x = acc[m][0] + bi.x + o.x;
            res.y = acc[m][1] + bi.y + o.y;
            res.z = acc[m][2] + bi.z + o.z;
            res.w = acc[m][3] + bi.w + o.w;
            *(float4*)(out + obase + 16 * m) = res;
        }
    }
}

extern "C" void kernel_launch(void* const* d_in, const int* in_sizes, int n_in,
                              void* d_out, int out_size, void* d_ws, size_t ws_size,
                              hipStream_t stream) {
    const float* obs   = (const float*)d_in[0];
    const float* rnn   = (const float*)d_in[1];
    const int*   alive = (const int*)d_in[2];
    const float* W     = (const float*)d_in[3];
    const float* bias  = (const float*)d_in[4];
    float* out = (float*)d_out;
    (void)in_sizes; (void)n_in; (void)d_ws; (void)ws_size; (void)out_size;

    commnet_fused<<<2048, 512, 0, stream>>>(obs, rnn, alive, W, bias, out);
}

// Round 4
// 181.896 us; speedup vs baseline: 1.1553x; 1.0951x over previous
//
#include <hip/hip_runtime.h>
#include <hip/hip_bf16.h>

// A=8 agents, B=64 envs, S=1024 seq, H=128 hidden.
#define AN 8
#define BN 64
#define SN 1024
#define HN 128
#define MP 136   // msg_lds row pitch (bf16 elems): 272B rows, 16B-aligned, bank-rotating

typedef __attribute__((ext_vector_type(8))) short bf16x8;
typedef __attribute__((ext_vector_type(4))) float f32x4;

__device__ __forceinline__ unsigned short f2bf(float f) {
    unsigned u = __builtin_bit_cast(unsigned, f);
    return (unsigned short)((u + 0x7fffu + ((u >> 16) & 1u)) >> 16);  // RNE
}

// Block tile: (b = b0, a = 0..7, s = s0..s0+15) -> 128 msg rows x 128 cols.
// msg row m = a*16 + s_local. Wave wv computes rows of agent a = wv.
__global__ __launch_bounds__(512) void commnet_fused(
    const float* __restrict__ obs,   // (A*B, S, H)
    const float* __restrict__ rnn,   // (S, B, A, H)
    const int*   __restrict__ alive, // (A, B, S, 1)
    const float* __restrict__ W,     // (H, H) [out, in]
    const float* __restrict__ bias,  // (H,)
    float* __restrict__ out)         // (A*B, S, H)
{
    // W as MFMA A-operand fragments (layout verified R0-R2):
    // lane l of tile (nt,ks) holds W[16*nt + (l&15)][32*ks + 8*(l>>4) + j]
    __shared__ bf16x8 Wfrag[8][4][64];            // 32 KiB
    __shared__ unsigned short msg[128 * MP];      // 34 KiB bf16 msg tile
    __shared__ float bias_lds[HN];
    __shared__ int   alive_lds[128];              // [a2*16 + s_local]
    __shared__ float scale_lds[128];              // [a*16 + s_local]

    const int tid  = threadIdx.x;
    const int lane = tid & 63;
    const int wv   = tid >> 6;          // 0..7 = agent a
    const int bid  = blockIdx.x;
    const int b0   = bid >> 6;          // 0..63
    const int s0   = (bid & 63) << 4;   // 0..1008

    // ---- issue rnn tile loads: 16 chunks of 4KB contiguous, 2 s per sweep ----
    float4 rv[8];
    {
        const int s_hi = tid >> 8;          // 0/1
        const int off  = (tid & 255) * 4;   // float offset in 4KB chunk
#pragma unroll
        for (int j = 0; j < 8; ++j) {
            const int s = s0 + 2 * j + s_hi;
            rv[j] = *(const float4*)(rnn + (size_t)(s * BN + b0) * (AN * HN) + off);
        }
    }

    // ---- alive + bias staging ----
    if (tid < 128) {
        alive_lds[tid] = alive[((tid >> 4) * BN + b0) * SN + s0 + (tid & 15)];
        bias_lds[tid]  = bias[tid];
    }

    // ---- W fragment pack (L2/L3-hot after first blocks) ----
    for (int e = tid; e < 8 * 4 * 64; e += 512) {
        int l  = e & 63;
        int ks = (e >> 6) & 3;
        int nt = e >> 8;
        int col = 16 * nt + (l & 15);
        int k0  = 32 * ks + 8 * (l >> 4);
        const float* wp = W + col * HN + k0;
        float4 w0 = *(const float4*)(wp);
        float4 w1 = *(const float4*)(wp + 4);
        bf16x8 f;
        f[0] = f2bf(w0.x); f[1] = f2bf(w0.y); f[2] = f2bf(w0.z); f[3] = f2bf(w0.w);
        f[4] = f2bf(w1.x); f[5] = f2bf(w1.y); f[6] = f2bf(w1.z); f[7] = f2bf(w1.w);
        Wfrag[nt][ks][l] = f;
    }
    __syncthreads();

    // ---- alive scales: scale[a][sl] = alive[a] ? 1/max(sum_a2,1) : 0 ----
    if (tid < 128) {
        const int sl = tid & 15;
        int asum = 0;
#pragma unroll
        for (int a2 = 0; a2 < AN; ++a2) asum += alive_lds[a2 * 16 + sl];
        scale_lds[tid] = alive_lds[tid] ? 1.0f / (float)(asum < 1 ? 1 : asum) : 0.0f;
    }
    __syncthreads();

    // ---- convert + scale -> bf16 msg tile in LDS ----
    {
        const int s_hi = tid >> 8;
        const int a    = (tid & 255) >> 5;
        const int h0   = (tid & 31) * 4;
#pragma unroll
        for (int j = 0; j < 8; ++j) {
            const int sl = 2 * j + s_hi;
            const float sc = scale_lds[a * 16 + sl];
            float4 v = rv[j];
            ushort4 p;
            p.x = f2bf(v.x * sc); p.y = f2bf(v.y * sc);
            p.z = f2bf(v.z * sc); p.w = f2bf(v.w * sc);
            *(ushort4*)&msg[(a * 16 + sl) * MP + h0] = p;
        }
    }
    __syncthreads();

    // ---- MFMA + epilogue (per wave: agent a = wv, 16 s-rows x 128 cols) ----
    const int r  = lane & 15;   // msg row within tile / out s-offset
    const int kg = lane >> 4;   // k-group / out col-group

    // obs prefetch: wave footprint = contiguous 8KB chunk
    const size_t base = (size_t)(wv * BN + b0) * (SN * HN)
                      + (size_t)(s0 + r) * HN + 4 * kg;
    float4 ob[8];
#pragma unroll
    for (int nt = 0; nt < 8; ++nt)
        ob[nt] = *(const float4*)(obs + base + 16 * nt);

    bf16x8 mb[4];
#pragma unroll
    for (int ks = 0; ks < 4; ++ks)
        mb[ks] = *(const bf16x8*)&msg[(16 * wv + r) * MP + 32 * ks + 8 * kg];

    f32x4 acc[8];
#pragma unroll
    for (int nt = 0; nt < 8; ++nt) acc[nt] = (f32x4){0.f, 0.f, 0.f, 0.f};
#pragma unroll
    for (int ks = 0; ks < 4; ++ks) {
#pragma unroll
        for (int nt = 0; nt < 8; ++nt)
            acc[nt] = __builtin_amdgcn_mfma_f32_16x16x32_bf16(
                Wfrag[nt][ks][lane], mb[ks], acc[nt], 0, 0, 0);
    }

#pragma unroll
    for (int nt = 0; nt < 8; ++nt) {
        float4 bi = *(const float4*)&bias_lds[16 * nt + 4 * kg];
        float4 o  = ob[nt];
        float4 res;
        res.x = acc[nt][0] + bi.x + o.x;
        res.y = acc[nt][1] + bi.y + o.y;
        res.z = acc[nt][2] + bi.z + o.z;
        res.w = acc[nt][3] + bi.w + o.w;
        *(float4*)(out + base + 16 * nt) = res;
    }
}

extern "C" void kernel_launch(void* const* d_in, const int* in_sizes, int n_in,
                              void* d_out, int out_size, void* d_ws, size_t ws_size,
                              hipStream_t stream) {
    const float* obs   = (const float*)d_in[0];
    const float* rnn   = (const float*)d_in[1];
    const int*   alive = (const int*)d_in[2];
    const float* W     = (const float*)d_in[3];
    const float* bias  = (const float*)d_in[4];
    float* out = (float*)d_out;
    (void)in_sizes; (void)n_in; (void)d_ws; (void)ws_size; (void)out_size;

    commnet_fused<<<64 * 64, 512, 0, stream>>>(obs, rnn, alive, W, bias, out);
}